// Round 7
// baseline (1715.596 us; speedup 1.0000x reference)
//
#include <hip/hip_runtime.h>

// Phi3 quantized MLP on MI355X (gfx950) — R7: 4 waves/SIMD within register budget.
// R6 post-mortem: wave-split blew the 128-reg cap (WRITE_SIZE 33->174 MB = scratch
// spill). R7: 256-thr blocks; GEMM1 tile 128x64 dual (64 acc/wave), GEMM2 128x128
// with h-sequential frags (64 acc + 16 a + 4 b live). launch_bounds(256,4).
// Act quant groups now 64 wide (block-local); GEMM2 rescales per K=64 half.

typedef float f32x4 __attribute__((ext_vector_type(4)));
typedef float f32x2 __attribute__((ext_vector_type(2)));
typedef int   i32x4 __attribute__((ext_vector_type(4)));

__device__ __forceinline__ void gload16(const void* g, void* l) {
  __builtin_amdgcn_global_load_lds(
      (const __attribute__((address_space(1))) void*)g,
      (__attribute__((address_space(3))) void*)l, 16, 0, 0);
}

// ---------------- quantize x: f32 -> int8, scale per (row-quad of 4, group of 128) ----------------
__global__ __launch_bounds__(256) void quant_x(const float* __restrict__ x,
                                               signed char* __restrict__ Xq,
                                               float* __restrict__ Xs4) {
  int g    = blockIdx.x;
  int rq   = blockIdx.y;
  int w    = threadIdx.x >> 6;
  int lane = threadIdx.x & 63;
  int row  = rq * 4 + w;
  __shared__ float wmax[4];
  const float2 v = *(const float2*)(x + (size_t)row * 3072 + g * 128 + lane * 2);
  float m = fmaxf(fabsf(v.x), fabsf(v.y));
#pragma unroll
  for (int s = 1; s < 64; s <<= 1) m = fmaxf(m, __shfl_xor(m, s));
  if (lane == 0) wmax[w] = m;
  __syncthreads();
  float m4 = fmaxf(fmaxf(wmax[0], wmax[1]), fmaxf(wmax[2], wmax[3]));
  float inv = m4 > 0.f ? 127.f / m4 : 0.f;
  int qa = (int)rintf(v.x * inv);
  int qb = (int)rintf(v.y * inv);
  unsigned short pk = (unsigned short)((qa & 0xff) | ((qb & 0xff) << 8));
  *(unsigned short*)(Xq + (size_t)row * 3072 + g * 128 + lane * 2) = pk;
  if (threadIdx.x == 0) Xs4[g * 1024 + rq] = m4 * (1.f / 127.f);
}

// ---------------- requant weights: int32 q,z -> int8 (q - z), exact ----------------
template <int K>
__global__ __launch_bounds__(256) void requant_k(const int* __restrict__ qw,
                                                 const int* __restrict__ qz,
                                                 signed char* __restrict__ W) {
  constexpr int KG = K / 128;
  constexpr int perrow = K / 8;
  int idx = blockIdx.x * 256 + threadIdx.x;
  int row = idx / perrow;
  int c8  = idx - row * perrow;
  int k   = c8 << 3;
  int z   = qz[row * KG + (k >> 7)];
  const int4* q4 = (const int4*)(qw + (size_t)row * K + k);
  int4 qa = q4[0];
  int4 qb = q4[1];
  int b0 = ((qa.x - z) & 0xff) | (((qa.y - z) & 0xff) << 8) |
           (((qa.z - z) & 0xff) << 16) | (((qa.w - z) & 0xff) << 24);
  int b1 = ((qb.x - z) & 0xff) | (((qb.y - z) & 0xff) << 8) |
           (((qb.z - z) & 0xff) << 16) | (((qb.w - z) & 0xff) << 24);
  int2 o; o.x = b0; o.y = b1;
  *(int2*)(W + (size_t)row * K + k) = o;
}

// ---------------- scale transpose: [R][G] -> [G][R] ----------------
__global__ __launch_bounds__(256) void transpose_sc(const float* __restrict__ in,
                                                    float* __restrict__ out,
                                                    int R, int G) {
  int idx = blockIdx.x * 256 + threadIdx.x;
  int r = idx / G;
  int g = idx - r * G;
  out[(size_t)g * R + r] = in[idx];
}

// LDS tiles XOR-swizzled: phys 16B chunk p of row holds logical chunk p^(row&7).

// ---------------- GEMM1: act = silu(x@Wg^T)*(x@Wu^T) ----------------
// Block tile 128(m) x 64(n), DUAL output. 4 waves, wave = 64x32 dual (64 f32 acc).
// Grid 4096: XCD x <- n-band of 16 n-tiles; m-major inside.
__global__ __launch_bounds__(256, 4) void gemm_gateup_i8(
    const signed char* __restrict__ Xq, const signed char* __restrict__ Wq,
    const float* __restrict__ Xs4,   // [24][1024]
    const float* __restrict__ GsT,   // [24][16384]
    signed char* __restrict__ act,   // [4096][8192]
    float* __restrict__ As4) {       // [128][1024]
  const int K = 3072;
  const int bid = blockIdx.x;
  const int xcd = bid & 7;
  const int j   = bid >> 3;                 // 0..511
  const int n0  = (xcd * 16 + (j & 15)) * 64;
  const int m0  = (j >> 4) * 128;
  __shared__ signed char lA[16384];
  __shared__ signed char lG[8192];
  __shared__ signed char lU[8192];
  __shared__ float rmax[2][128];
  __shared__ float rmax4[32];

  const int tid  = threadIdx.x;
  const int l    = tid & 63;
  const int quad = l >> 4;
  const int l16  = l & 15;
  const int wave = tid >> 6;
  const int wcI  = wave & 1;
  const int wr   = (wave >> 1) * 64;
  const int wc   = wcI * 32;

  f32x2 fg[4][2][2] = {};
  f32x2 fu[4][2][2] = {};

  int offA[4], offW[2];
#pragma unroll
  for (int jj = 0; jj < 4; ++jj) {
    int c   = tid + 256 * jj;
    int row = c >> 3;
    offA[jj] = row * K + (((c & 7) ^ (row & 7)) * 16);
  }
#pragma unroll
  for (int jj = 0; jj < 2; ++jj) {
    int c   = tid + 256 * jj;
    int row = c >> 3;                       // 0..63
    offW[jj] = row * K + (((c & 7) ^ (row & 7)) * 16);
  }
  const signed char* baseA = Xq + (size_t)m0 * K;
  const signed char* baseG = Wq + (size_t)n0 * K;
  const signed char* baseU = Wq + (size_t)(8192 + n0) * K;

  int aoff[2][4], boff[2][2];
#pragma unroll
  for (int h = 0; h < 2; ++h) {
    int slot = h * 4 + quad;
#pragma unroll
    for (int i = 0; i < 4; ++i) {
      int ra = wr + i * 16 + l16;
      aoff[h][i] = ra * 128 + ((slot ^ (ra & 7)) * 16);
    }
#pragma unroll
    for (int jj = 0; jj < 2; ++jj) {
      int rb = wc + jj * 16 + l16;          // 0..63
      boff[h][jj] = rb * 128 + ((slot ^ (rb & 7)) * 16);
    }
  }
  const int qbase = (m0 >> 2) + (wr >> 2) + quad;

  for (int g = 0; g < 24; ++g) {
    const int kk = g << 7;
#pragma unroll
    for (int jj = 0; jj < 4; ++jj)
      gload16(baseA + offA[jj] + kk, lA + (tid + 256 * jj) * 16);
#pragma unroll
    for (int jj = 0; jj < 2; ++jj) {
      gload16(baseG + offW[jj] + kk, lG + (tid + 256 * jj) * 16);
      gload16(baseU + offW[jj] + kk, lU + (tid + 256 * jj) * 16);
    }
    float sxq[4], sg[2], su[2];
#pragma unroll
    for (int i = 0; i < 4; ++i) sxq[i] = Xs4[g * 1024 + qbase + i * 4];
#pragma unroll
    for (int jj = 0; jj < 2; ++jj) {
      sg[jj] = GsT[g * 16384 + n0 + wc + jj * 16 + l16];
      su[jj] = GsT[g * 16384 + 8192 + n0 + wc + jj * 16 + l16];
    }
    __syncthreads();

#pragma unroll
    for (int h = 0; h < 2; ++h) {
      i32x4 a[4];
#pragma unroll
      for (int i = 0; i < 4; ++i) a[i] = *(const i32x4*)(lA + aoff[h][i]);
#pragma unroll
      for (int jj = 0; jj < 2; ++jj) {
        i32x4 bg = *(const i32x4*)(lG + boff[h][jj]);
        i32x4 bu = *(const i32x4*)(lU + boff[h][jj]);
#pragma unroll
        for (int i = 0; i < 4; ++i) {
          i32x4 zero = {0, 0, 0, 0};
          i32x4 ig = __builtin_amdgcn_mfma_i32_16x16x64_i8(a[i], bg, zero, 0, 0, 0);
          i32x4 iu = __builtin_amdgcn_mfma_i32_16x16x64_i8(a[i], bu, zero, 0, 0, 0);
          float pgs = sxq[i] * sg[jj];
          float pus = sxq[i] * su[jj];
          f32x2 pg2 = {pgs, pgs};
          f32x2 pu2 = {pus, pus};
          f32x2 g01 = {(float)ig[0], (float)ig[1]};
          f32x2 g23 = {(float)ig[2], (float)ig[3]};
          f32x2 u01 = {(float)iu[0], (float)iu[1]};
          f32x2 u23 = {(float)iu[2], (float)iu[3]};
          fg[i][jj][0] = __builtin_elementwise_fma(g01, pg2, fg[i][jj][0]);
          fg[i][jj][1] = __builtin_elementwise_fma(g23, pg2, fg[i][jj][1]);
          fu[i][jj][0] = __builtin_elementwise_fma(u01, pu2, fu[i][jj][0]);
          fu[i][jj][1] = __builtin_elementwise_fma(u23, pu2, fu[i][jj][1]);
        }
      }
    }
    __syncthreads();
  }

  // ---- epilogue: silu(g)*u -> quad absmax (64-col group) -> int8 ----
  float av[4][2][4];
#pragma unroll
  for (int i = 0; i < 4; ++i)
#pragma unroll
    for (int jj = 0; jj < 2; ++jj)
#pragma unroll
      for (int r = 0; r < 4; ++r) {
        float gv = fg[i][jj][r >> 1][r & 1];
        float uv = fu[i][jj][r >> 1][r & 1];
        av[i][jj][r] = (gv / (1.f + __expf(-gv))) * uv;
      }

#pragma unroll
  for (int i = 0; i < 4; ++i)
#pragma unroll
    for (int r = 0; r < 4; ++r) {
      float m = fmaxf(fabsf(av[i][0][r]), fabsf(av[i][1][r]));
      m = fmaxf(m, __shfl_xor(m, 1));
      m = fmaxf(m, __shfl_xor(m, 2));
      m = fmaxf(m, __shfl_xor(m, 4));
      m = fmaxf(m, __shfl_xor(m, 8));
      if (l16 == 0) rmax[wcI][wr + i * 16 + quad * 4 + r] = m;
    }
  __syncthreads();
  if (tid < 32) {
    float m4 = 0.f;
#pragma unroll
    for (int k = 0; k < 4; ++k)
      m4 = fmaxf(m4, fmaxf(rmax[0][tid * 4 + k], rmax[1][tid * 4 + k]));
    rmax4[tid] = m4;
    As4[(n0 >> 6) * 1024 + (m0 >> 2) + tid] = m4 * (1.f / 127.f);
  }
  __syncthreads();

#pragma unroll
  for (int i = 0; i < 4; ++i) {
    float mq = rmax4[(wr >> 2) + i * 4 + quad];
    float inv = mq > 0.f ? 127.f / mq : 0.f;
#pragma unroll
    for (int r = 0; r < 4; ++r) {
      int mrow = wr + i * 16 + quad * 4 + r;
#pragma unroll
      for (int jj = 0; jj < 2; ++jj) {
        int q = (int)rintf(av[i][jj][r] * inv);
        lA[mrow * 64 + wc + jj * 16 + l16] = (signed char)q;
      }
    }
  }
  __syncthreads();

#pragma unroll
  for (int t = 0; t < 2; ++t) {
    int c = tid + 256 * t;
    int row = c >> 2;
    int col = (c & 3) * 16;
    *(int4*)(act + (size_t)(m0 + row) * 8192 + n0 + col) = *(const int4*)(lA + row * 64 + col);
  }
}

// ---------------- GEMM2: out = dequant(act)@Wd^T + bias ----------------
// 128x128 tile, 4 waves x 64x64; h-sequential frags; act scale per K=64 group.
__global__ __launch_bounds__(256, 4) void gemm_down_i8(
    const signed char* __restrict__ Aq, const signed char* __restrict__ Wq,
    const float* __restrict__ As4,   // [128][1024]
    const float* __restrict__ DsT,   // [64][3072]
    const float* __restrict__ bias,
    float* __restrict__ out) {
  const int K = 8192;
  const int bid = blockIdx.x;
  const int xcd = bid & 7;
  const int jb  = bid >> 3;
  const int jn  = jb % 12;
  const int jm  = jb / 12;
  const int n0  = (12 * (xcd & 1) + jn) * 128;
  const int m0  = (8 * (xcd >> 1) + jm) * 128;
  __shared__ signed char lA[16384];
  __shared__ signed char lB[16384];

  const int tid  = threadIdx.x;
  const int l    = tid & 63;
  const int quad = l >> 4;
  const int l16  = l & 15;
  const int wave = tid >> 6;
  const int wr   = (wave >> 1) * 64;
  const int wc   = (wave & 1) * 64;

  f32x2 fc[4][4][2] = {};

  int off[4];
#pragma unroll
  for (int jj = 0; jj < 4; ++jj) {
    int c   = tid + 256 * jj;
    int row = c >> 3;
    off[jj] = row * K + (((c & 7) ^ (row & 7)) * 16);
  }
  const signed char* baseA = Aq + (size_t)m0 * K;
  const signed char* baseB = Wq + (size_t)n0 * K;

  int aoff[2][4], boff[2][4];
#pragma unroll
  for (int h = 0; h < 2; ++h) {
    int slot = h * 4 + quad;
#pragma unroll
    for (int i = 0; i < 4; ++i) {
      int ra = wr + i * 16 + l16;
      aoff[h][i] = ra * 128 + ((slot ^ (ra & 7)) * 16);
      int rb = wc + i * 16 + l16;
      boff[h][i] = rb * 128 + ((slot ^ (rb & 7)) * 16);
    }
  }
  const int qbase = (m0 >> 2) + (wr >> 2) + quad;

  for (int it = 0; it < 64; ++it) {
    const int kk = it << 7;
#pragma unroll
    for (int jj = 0; jj < 4; ++jj) {
      gload16(baseA + off[jj] + kk, lA + (tid + 256 * jj) * 16);
      gload16(baseB + off[jj] + kk, lB + (tid + 256 * jj) * 16);
    }
    float sxq[2][4], sn[4];
#pragma unroll
    for (int h = 0; h < 2; ++h)
#pragma unroll
      for (int i = 0; i < 4; ++i)
        sxq[h][i] = As4[(it * 2 + h) * 1024 + qbase + i * 4];
#pragma unroll
    for (int jj = 0; jj < 4; ++jj)
      sn[jj] = DsT[it * 3072 + n0 + wc + jj * 16 + l16];
    __syncthreads();

#pragma unroll
    for (int h = 0; h < 2; ++h) {
      i32x4 a[4];
#pragma unroll
      for (int i = 0; i < 4; ++i) a[i] = *(const i32x4*)(lA + aoff[h][i]);
#pragma unroll
      for (int jj = 0; jj < 4; ++jj) {
        i32x4 b = *(const i32x4*)(lB + boff[h][jj]);
#pragma unroll
        for (int i = 0; i < 4; ++i) {
          i32x4 zero = {0, 0, 0, 0};
          i32x4 ic = __builtin_amdgcn_mfma_i32_16x16x64_i8(a[i], b, zero, 0, 0, 0);
          float ps = sxq[h][i] * sn[jj];
          f32x2 p2 = {ps, ps};
          f32x2 c01 = {(float)ic[0], (float)ic[1]};
          f32x2 c23 = {(float)ic[2], (float)ic[3]};
          fc[i][jj][0] = __builtin_elementwise_fma(c01, p2, fc[i][jj][0]);
          fc[i][jj][1] = __builtin_elementwise_fma(c23, p2, fc[i][jj][1]);
        }
      }
    }
    __syncthreads();
  }

  float bj[4];
#pragma unroll
  for (int jj = 0; jj < 4; ++jj) bj[jj] = bias[n0 + wc + jj * 16 + l16];

#pragma unroll
  for (int i = 0; i < 4; ++i)
#pragma unroll
    for (int jj = 0; jj < 4; ++jj)
#pragma unroll
      for (int r = 0; r < 4; ++r) {
        int m = m0 + wr + i * 16 + quad * 4 + r;
        int n = n0 + wc + jj * 16 + l16;
        out[(size_t)m * 3072 + n] = fc[i][jj][r >> 1][r & 1] + bj[jj];
      }
}

extern "C" void kernel_launch(void* const* d_in, const int* in_sizes, int n_in,
                              void* d_out, int out_size, void* d_ws, size_t ws_size,
                              hipStream_t stream) {
  const float* x        = (const float*)d_in[0];
  const int*   gup_qw   = (const int*)d_in[1];
  const int*   gup_qz   = (const int*)d_in[2];
  const float* gup_sc   = (const float*)d_in[3];
  const int*   down_qw  = (const int*)d_in[4];
  const int*   down_qz  = (const int*)d_in[5];
  const float* down_sc  = (const float*)d_in[6];
  const float* down_b   = (const float*)d_in[7];
  float* out = (float*)d_out;

  char* ws = (char*)d_ws;
  signed char* Xq    = (signed char*)(ws);                 // 12,582,912
  signed char* Wgupq = (signed char*)(ws + 12582912);      // 50,331,648
  signed char* Wdnq  = (signed char*)(ws + 62914560);      // 25,165,824
  signed char* Actq  = (signed char*)(ws + 88080384);      // 33,554,432
  float* Xs4 = (float*)(ws + 121634816);                   // 24x1024
  float* GsT = (float*)(ws + 121733120);                   // 24x16384
  float* DsT = (float*)(ws + 123305984);                   // 64x3072
  float* As4 = (float*)(ws + 124092416);                   // 128x1024

  quant_x<<<dim3(24, 1024), 256, 0, stream>>>(x, Xq, Xs4);
  requant_k<3072><<<24576, 256, 0, stream>>>(gup_qw, gup_qz, Wgupq);
  requant_k<8192><<<12288, 256, 0, stream>>>(down_qw, down_qz, Wdnq);
  transpose_sc<<<1536, 256, 0, stream>>>(gup_sc, GsT, 16384, 24);
  transpose_sc<<<768, 256, 0, stream>>>(down_sc, DsT, 3072, 64);
  gemm_gateup_i8<<<4096, 256, 0, stream>>>(Xq, Wgupq, Xs4, GsT, Actq, As4);
  gemm_down_i8<<<768, 256, 0, stream>>>(Actq, Wdnq, As4, DsT, down_b, out);
}